// Round 1
// baseline (328.135 us; speedup 1.0000x reference)
//
#include <hip/hip_runtime.h>
#include <hip/hip_bf16.h>

typedef unsigned short u16;
typedef __attribute__((ext_vector_type(8))) short short8;   // 8 bf16 = 4 VGPR (MFMA A/B frag)
typedef __attribute__((ext_vector_type(4))) float floatx4;  // MFMA C/D frag

static __device__ __forceinline__ u16 f2bf(float x) {
    __hip_bfloat16 h = __float2bfloat16(x);
    union { __hip_bfloat16 h; u16 u; } cv; cv.h = h; return cv.u;
}
static __device__ __forceinline__ float bf2f(u16 u) {
    union { u16 u; __hip_bfloat16 h; } cv; cv.u = u;
    return __bfloat162float(cv.h);
}

// ---------------- elementwise fp32 -> bf16 convert (feats) ----------------
__global__ void k_cvt(const float* __restrict__ in, u16* __restrict__ out) {
    int i = (blockIdx.x * 256 + threadIdx.x) * 4;
    float4 v = *(const float4*)&in[i];
    out[i + 0] = f2bf(v.x); out[i + 1] = f2bf(v.y);
    out[i + 2] = f2bf(v.z); out[i + 3] = f2bf(v.w);
}

// ---------- tiled transpose fp32[R][C] -> bf16[C][R] (weight prep) ----------
__global__ void k_transpose(const float* __restrict__ in, u16* __restrict__ out,
                            int R, int Cn) {
    __shared__ float t[64][65];
    int c  = threadIdx.x & 63;
    int r0 = threadIdx.x >> 6;
    int bx = blockIdx.x, by = blockIdx.y;
    for (int rr = r0; rr < 64; rr += 4)
        t[rr][c] = in[(long)(by * 64 + rr) * Cn + bx * 64 + c];
    __syncthreads();
    for (int rr = r0; rr < 64; rr += 4)
        out[(long)(bx * 64 + rr) * R + by * 64 + c] = f2bf(t[c][rr]);
}

// ---------------- q/k projections from fpjT[b,h,d,n] ----------------
__global__ void k_qk(const u16* __restrict__ fpjT,
                     const float* __restrict__ qw, const float* __restrict__ kw,
                     const float* __restrict__ qb, const float* __restrict__ kb,
                     float* __restrict__ qo, float* __restrict__ ko) {
    int bh = blockIdx.y;
    int n  = blockIdx.x * 256 + threadIdx.x;
    __shared__ float wq[256], wk[256];
    wq[threadIdx.x] = qw[threadIdx.x];
    wk[threadIdx.x] = kw[threadIdx.x];
    __syncthreads();
    const u16* base = fpjT + ((long)bh << 18) + n;   // bh*256*1024
    float qa = 0.f, ka = 0.f;
    for (int d = 0; d < 256; d++) {
        float v = bf2f(base[(long)d << 10]);         // coalesced over n
        qa += v * wq[d]; ka += v * wk[d];
    }
    qo[(bh << 10) + n] = qa + qb[0];
    ko[(bh << 10) + n] = ka + kb[0];
}

// ------- scores: P~ = adj * exp(leaky(q_i+k_j)), rl = 1/rowsum -------
// No max-subtraction needed: q,k ~ O(1) so exp stays in fp32 range; masked
// entries are exactly 0 (matches fp32 ref where exp(-1e7-m) underflows to 0).
__global__ void k_scores(const float* __restrict__ adj, const float* __restrict__ qv,
                         const float* __restrict__ kv, u16* __restrict__ P,
                         float* __restrict__ rl) {
    int bx = blockIdx.x;              // b*1024 + i
    int b = bx >> 10, i = bx & 1023;
    int tid = threadIdx.x;
    __shared__ float arow[1024];
    __shared__ float red[4];
    *(float4*)&arow[tid * 4] = *(const float4*)&adj[((long)bx << 10) + tid * 4];
    __syncthreads();
    for (int h = 0; h < 8; h++) {
        int bh = b * 8 + h;
        float qs = qv[(bh << 10) + i];
        float lsum = 0.f;
        #pragma unroll
        for (int jj = 0; jj < 4; jj++) {
            int j = jj * 256 + tid;
            float s = qs + kv[(bh << 10) + j];
            s = s > 0.f ? s : 0.01f * s;            // leaky_relu
            float p = arow[j] > 0.f ? __expf(s) : 0.f;
            lsum += p;
            P[((long)bh << 20) + ((long)i << 10) + j] = f2bf(p);
        }
        #pragma unroll
        for (int off = 32; off > 0; off >>= 1) lsum += __shfl_down(lsum, off);
        if ((tid & 63) == 0) red[tid >> 6] = lsum;
        __syncthreads();
        if (tid == 0) {
            float l = red[0] + red[1] + red[2] + red[3];
            rl[(bh << 10) + i] = l > 0.f ? 1.f / l : 0.f;
        }
        __syncthreads();
    }
}

// ---------------- NT bf16 GEMM: C = A[M][K] * Bt[N][K]^T ----------------
// 128x128 tile, BK=32, 4 waves (2x2), each wave 4x4 of 16x16x32 MFMA.
// LDS rows padded to 40 elems (80 B) -> balanced banks for ds_read_b128.
// EPI 1: bf16 transposed store to fpjT[b, col, n] (+bias)
// EPI 2: bf16 store * rl[row] into outh (ldc=2048, per-batch col offset)
// EPI 3: fp32 sigmoid(acc + bias + resid) store (ldc=256)
template <int EPI>
__global__ __launch_bounds__(256, 2)
void gemm_nt(const u16* __restrict__ A, const u16* __restrict__ Bt,
             int lda, int ldb, int M, int N, int K,
             long strideAz, long strideBz,
             void* __restrict__ Cv, long cOffB, long cOffH,
             const float* __restrict__ bias,
             const float* __restrict__ rl,
             const float* __restrict__ resid) {
    __shared__ u16 As[128 * 40];
    __shared__ u16 Bs[128 * 40];
    int z = blockIdx.z;
    A  += (long)z * strideAz;
    Bt += (long)z * strideBz;
    int rowBase = blockIdx.y * 128;
    int colBase = blockIdx.x * 128;
    int tid  = threadIdx.x;
    int wave = tid >> 6, lane = tid & 63;
    int wr = wave >> 1, wc = wave & 1;
    int q  = lane >> 4, n16 = lane & 15;

    floatx4 acc[4][4] = {};

    int sm = tid >> 2;          // 0..63 (staging row)
    int sk = (tid & 3) * 8;     // k-chunk within BK

    for (int k0 = 0; k0 < K; k0 += 32) {
        int4 a0 = *(const int4*)&A[(long)(rowBase + sm) * lda + k0 + sk];
        int4 a1 = *(const int4*)&A[(long)(rowBase + sm + 64) * lda + k0 + sk];
        int4 b0 = *(const int4*)&Bt[(long)(colBase + sm) * ldb + k0 + sk];
        int4 b1 = *(const int4*)&Bt[(long)(colBase + sm + 64) * ldb + k0 + sk];
        __syncthreads();   // previous iter's frag reads done
        *(int4*)&As[sm * 40 + sk]        = a0;
        *(int4*)&As[(sm + 64) * 40 + sk] = a1;
        *(int4*)&Bs[sm * 40 + sk]        = b0;
        *(int4*)&Bs[(sm + 64) * 40 + sk] = b1;
        __syncthreads();
        short8 af[4], bfr[4];
        #pragma unroll
        for (int i = 0; i < 4; i++)
            af[i] = *(short8*)&As[(wr * 64 + i * 16 + n16) * 40 + q * 8];
        #pragma unroll
        for (int i = 0; i < 4; i++)
            bfr[i] = *(short8*)&Bs[(wc * 64 + i * 16 + n16) * 40 + q * 8];
        #pragma unroll
        for (int mi = 0; mi < 4; mi++)
            #pragma unroll
            for (int ni = 0; ni < 4; ni++)
                acc[mi][ni] = __builtin_amdgcn_mfma_f32_16x16x32_bf16(
                    af[mi], bfr[ni], acc[mi][ni], 0, 0, 0);
    }

    u16*   Cb  = (u16*)Cv;
    u16*   Cb2 = (u16*)Cv + (long)(z >> 3) * cOffB + (long)(z & 7) * cOffH;
    float* Cf  = (float*)Cv;
    #pragma unroll
    for (int mi = 0; mi < 4; mi++) {
        #pragma unroll
        for (int r = 0; r < 4; r++) {
            int grow = rowBase + wr * 64 + mi * 16 + q * 4 + r;
            #pragma unroll
            for (int ni = 0; ni < 4; ni++) {
                int gcol = colBase + wc * 64 + ni * 16 + n16;
                float v = acc[mi][ni][r];
                if (EPI == 1) {
                    v += bias[gcol];
                    int b = grow >> 10, nn = grow & 1023;
                    Cb[(((long)(b * 2048 + gcol)) << 10) + nn] = f2bf(v);
                } else if (EPI == 2) {
                    v *= rl[(z << 10) + grow];
                    Cb2[(long)grow * 2048 + gcol] = f2bf(v);
                } else {
                    v += bias[gcol] + resid[(long)grow * 256 + gcol];
                    Cf[(long)grow * 256 + gcol] = 1.f / (1.f + __expf(-v));
                }
            }
        }
    }
}

extern "C" void kernel_launch(void* const* d_in, const int* in_sizes, int n_in,
                              void* d_out, int out_size, void* d_ws, size_t ws_size,
                              hipStream_t stream) {
    const float* feats = (const float*)d_in[0];
    const float* adj   = (const float*)d_in[1];
    const float* fc_w  = (const float*)d_in[2];
    const float* fc_b  = (const float*)d_in[3];
    const float* q_w   = (const float*)d_in[4];
    const float* q_b   = (const float*)d_in[5];
    const float* k_w   = (const float*)d_in[6];
    const float* k_b   = (const float*)d_in[7];
    const float* fp_w  = (const float*)d_in[8];
    const float* fp_b  = (const float*)d_in[9];

    char* ws = (char*)d_ws;
    u16*   featsB = (u16*)ws;   ws += (size_t)2097152 * 2;   // [8192][256] bf16
    u16*   fcwT   = (u16*)ws;   ws += (size_t)524288 * 2;    // [2048][256] bf16
    u16*   fpwT   = (u16*)ws;   ws += (size_t)524288 * 2;    // [256][2048] bf16
    u16*   fpjT   = (u16*)ws;   ws += (size_t)16777216 * 2;  // [b,h,d,n] bf16
    float* qv     = (float*)ws; ws += (size_t)65536 * 4;     // [b,h,n]
    float* kv     = (float*)ws; ws += (size_t)65536 * 4;
    float* rl     = (float*)ws; ws += (size_t)65536 * 4;
    u16*   outh   = (u16*)ws;   ws += (size_t)16777216 * 2;  // [(b,n)][(h,d)] bf16
    u16*   P      = (u16*)ws;   ws += (size_t)67108864 * 2;  // [bh][i][j] bf16

    // setup: conversions + weight transposes
    k_cvt<<<2048, 256, 0, stream>>>(feats, featsB);
    k_transpose<<<dim3(32, 4), 256, 0, stream>>>(fc_w, fcwT, 256, 2048);
    k_transpose<<<dim3(4, 32), 256, 0, stream>>>(fp_w, fpwT, 2048, 256);

    // G1: feat_proj (transposed store into fpjT)
    gemm_nt<1><<<dim3(16, 64, 1), 256, 0, stream>>>(
        featsB, fcwT, 256, 256, 8192, 2048, 256, 0, 0,
        (void*)fpjT, 0, 0, fc_b, nullptr, nullptr);

    // q, k
    k_qk<<<dim3(4, 64), 256, 0, stream>>>(fpjT, q_w, k_w, q_b, k_b, qv, kv);

    // scores P~ and 1/l
    k_scores<<<8192, 256, 0, stream>>>(adj, qv, kv, P, rl);

    // G2: out_h = (P~ @ V) / l, batched over 64 (b,h)
    gemm_nt<2><<<dim3(2, 8, 64), 256, 0, stream>>>(
        P, fpjT, 1024, 1024, 1024, 256, 1024,
        (long)1 << 20, (long)1 << 18,
        (void*)outh, 2097152, 256, nullptr, rl, nullptr);

    // G3: sigmoid(outh @ fp_w + fp_b + feats)
    gemm_nt<3><<<dim3(2, 64, 1), 256, 0, stream>>>(
        outh, fpwT, 2048, 2048, 8192, 256, 2048, 0, 0,
        d_out, 0, 0, fp_b, nullptr, feats);
}